// Round 13
// baseline (2680.128 us; speedup 1.0000x reference)
//
#include <hip/hip_runtime.h>

#define HID 1024
#define G4 4096
#define TCH 128
#define NCH 4
#define NWG 256

typedef short short8 __attribute__((ext_vector_type(8)));
typedef float f32x4 __attribute__((ext_vector_type(4)));
typedef unsigned int u32x4 __attribute__((ext_vector_type(4)));

static __device__ __forceinline__ unsigned short f2bf(float f) {
    unsigned int u = __builtin_bit_cast(unsigned int, f);
    u += 0x7fffu + ((u >> 16) & 1u);
    return (unsigned short)(u >> 16);
}
static __device__ __forceinline__ unsigned short f2h(float v) {
    _Float16 h = (_Float16)v;
    return __builtin_bit_cast(unsigned short, h);
}
static __device__ __forceinline__ float h2f(unsigned short u) {
    return (float)__builtin_bit_cast(_Float16, u);
}

// fp32 -> bf16 bulk convert (n8 groups of 8)
__global__ void cvt_mat(const float* __restrict__ src, unsigned short* __restrict__ dst, int n8) {
    int idx = blockIdx.x * blockDim.x + threadIdx.x;
    if (idx >= n8) return;
    const float* s = src + (size_t)idx * 8;
    float4 a = *(const float4*)s;
    float4 b = *(const float4*)(s + 4);
    short8 v;
    v[0]=(short)f2bf(a.x); v[1]=(short)f2bf(a.y); v[2]=(short)f2bf(a.z); v[3]=(short)f2bf(a.w);
    v[4]=(short)f2bf(b.x); v[5]=(short)f2bf(b.y); v[6]=(short)f2bf(b.z); v[7]=(short)f2bf(b.w);
    *(short8*)(dst + (size_t)idx * 8) = v;
}

// zero state region (hcan, cws, hx), combine biases, bump per-replay nonce
__global__ void init_kernel(const float* __restrict__ bih, const float* __restrict__ bhh,
                            float* __restrict__ biasc, unsigned int* __restrict__ zbase,
                            int nz, unsigned int* __restrict__ nonce) {
    int i = blockIdx.x * blockDim.x + threadIdx.x;
    if (i < nz) zbase[i] = 0u;
    if (i < G4) biasc[i] = bih[i] + bhh[i];
    if (i == 0) nonce[0] = nonce[0] + 1u;
}

// xg[m][g] = sum_k x_chunk[m][k]*Wih[g][k], m = tl*64 + n; output f16 bits.
__global__ __launch_bounds__(256) void xg_gemm(
    const float* __restrict__ x,            // [64][512][1024] fp32
    const unsigned short* __restrict__ wb,  // Wih_bf [4096][1024]
    unsigned short* __restrict__ xg,        // [TCH*64][4096] f16 chunk
    int t0) {
    __shared__ unsigned short Al[128][72];
    __shared__ unsigned short Bl[128][72];
    const int tid = threadIdx.x, w = tid >> 6, lane = tid & 63;
    const int bm = blockIdx.x >> 5, bn = blockIdx.x & 31;
    const int wr = w >> 1, wc = w & 1;
    const int fr = lane & 15, kg = lane >> 4;
    f32x4 acc[4][4];
    #pragma unroll
    for (int i = 0; i < 4; ++i)
        #pragma unroll
        for (int j = 0; j < 4; ++j) acc[i][j] = (f32x4){0.f,0.f,0.f,0.f};

    for (int kt = 0; kt < 16; ++kt) {
        __syncthreads();
        #pragma unroll
        for (int c = 0; c < 4; ++c) {
            int idx = c * 256 + tid;
            int row = idx >> 3, co = (idx & 7) * 8;
            int m = bm * 128 + row;
            const float* sp = x + ((size_t)(m & 63) * 512 + (size_t)(t0 + (m >> 6))) * 1024
                                + kt * 64 + co;
            float4 a = *(const float4*)sp;
            float4 b = *(const float4*)(sp + 4);
            short8 v;
            v[0]=(short)f2bf(a.x); v[1]=(short)f2bf(a.y); v[2]=(short)f2bf(a.z); v[3]=(short)f2bf(a.w);
            v[4]=(short)f2bf(b.x); v[5]=(short)f2bf(b.y); v[6]=(short)f2bf(b.z); v[7]=(short)f2bf(b.w);
            *(short8*)&Al[row][co] = v;
            *(short8*)&Bl[row][co] = *(const short8*)(wb + (size_t)(bn * 128 + row) * 1024 + kt * 64 + co);
        }
        __syncthreads();
        #pragma unroll
        for (int kb = 0; kb < 2; ++kb) {
            short8 af[4], bf_[4];
            #pragma unroll
            for (int mi = 0; mi < 4; ++mi)
                af[mi] = *(const short8*)&Al[wr*64 + mi*16 + fr][kb*32 + kg*8];
            #pragma unroll
            for (int ni = 0; ni < 4; ++ni)
                bf_[ni] = *(const short8*)&Bl[wc*64 + ni*16 + fr][kb*32 + kg*8];
            #pragma unroll
            for (int mi = 0; mi < 4; ++mi)
                #pragma unroll
                for (int ni = 0; ni < 4; ++ni)
                    acc[mi][ni] = __builtin_amdgcn_mfma_f32_16x16x32_bf16(af[mi], bf_[ni], acc[mi][ni], 0, 0, 0);
        }
    }
    #pragma unroll
    for (int mi = 0; mi < 4; ++mi)
        #pragma unroll
        for (int ni = 0; ni < 4; ++ni)
            #pragma unroll
            for (int r = 0; r < 4; ++r) {
                int row = bm*128 + wr*64 + mi*16 + kg*4 + r;
                int col = bn*128 + wc*64 + ni*16 + fr;
                xg[(size_t)row * 4096 + col] = f2h(acc[mi][ni][r]);
            }
}

// Persistent LSTM chunk (128 steps). R12 structure; ONE change: the A-tile has only
// 8 real batch rows, so hA stores 8 rows (32 KB total) and lanes with row>=8 read
// the SAME LDS address as (row&7) -> same-address broadcast (free, m136) -> unique
// LDS accesses halve (256->128 KB/step/WG worth of unique traffic) and residual
// conflicts drop 8-way -> 4-way. A rows 8..15 become duplicates of 0..7; C rows
// 8..15 are therefore duplicates and are never read (pointwise uses kg<2 only).
// Math for rows 0..7 is bit-identical to R12.
__global__ __launch_bounds__(512, 2) void lstm_persist(
    const unsigned short* __restrict__ whh,   // Whh_bf [4096][1024]
    const unsigned short* __restrict__ xg,    // [TCH*64][4096] f16 bits
    const float* __restrict__ biasc,          // [4096]
    unsigned short* __restrict__ hcan,        // [64][1024] bf16 chunk-boundary h
    unsigned int* __restrict__ hx,            // [2 par][8 G][8][1024] u32 tagged h
    float* __restrict__ cws,                  // [64][1024] chunk-boundary c
    const unsigned int* __restrict__ nonce,   // [1]
    float* __restrict__ y, int t0) {
    __shared__ unsigned short hA[2][8192];    // [par][8][1024] bf16, XOR-swizzled

    const int tid = threadIdx.x, w = tid >> 6, lane = tid & 63;
    const int G = (int)(blockIdx.x >> 5);
    const int l = (int)(blockIdx.x & 31);

    const int c  = lane & 15, kg = lane >> 4;
    const int q  = c & 3;                  // gate type of this lane's B column
    const int e  = c >> 2;                 // unit-within-4 of this lane's B column
    const int jg = l * 32 + w * 4 + e;     // global hidden unit (output lanes <32)
    const int nloc = kg * 4 + q;           // group-local batch row (output lanes <32)
    const unsigned int nonce6 = nonce[0] & 63u;

    short8 bfr[32];   // Whh row (q*1024 + jg), K=1024
    {
        const unsigned short* wp = whh + ((size_t)(q * 1024 + jg) << 10) + kg * 8;
        #pragma unroll
        for (int kb = 0; kb < 32; ++kb) bfr[kb] = *(const short8*)(wp + kb * 32);
    }
    const float bi = biasc[jg],        bfv = biasc[1024 + jg];
    const float bg = biasc[2048 + jg], bov = biasc[3072 + jg];

    float creg = 0.f;
    if (lane < 32) creg = cws[((size_t)(G * 8 + nloc) << 10) + jg];
    __syncthreads();

    const int sn = w;   // staging batch row 0..7 (one per wave)

    for (int s = 0; s < TCH; ++s) {
        const int t = t0 + s;
        // ---- xg prefetch (4 scalar loads; complete under the poll) ----
        unsigned short xi = 0, xf = 0, xgv = 0, xo = 0;
        if (lane < 32) {
            const unsigned short* xp = xg + ((size_t)(s * 64 + G * 8 + nloc) << 12) + jg;
            xi = xp[0]; xf = xp[1024]; xgv = xp[2048]; xo = xp[3072];
        }
        // ---- acquire h(t) row sn (poll-with-data), stage into hA[s&1] ----
        short8 v0, v1;
        if (s == 0) {
            const unsigned short* hp = hcan + ((size_t)(G * 8 + sn) << 10) + lane * 16;
            v0 = *(const short8*)hp;
            v1 = *(const short8*)(hp + 8);
        } else {
            const unsigned int* pp = hx + ((size_t)((t & 1) * 8 + G)) * 8192 + sn * 1024 + lane * 16;
            const unsigned int ttag = (nonce6 << 10) | ((unsigned)t & 1023u);
            u32x4 w0, w1, w2, w3;
            int guard = 0;
            while (true) {
                asm volatile("global_load_dwordx4 %0, %1, off sc0 sc1" : "=v"(w0) : "v"(pp)      : "memory");
                asm volatile("global_load_dwordx4 %0, %1, off sc0 sc1" : "=v"(w1) : "v"(pp + 4)  : "memory");
                asm volatile("global_load_dwordx4 %0, %1, off sc0 sc1" : "=v"(w2) : "v"(pp + 8)  : "memory");
                asm volatile("global_load_dwordx4 %0, %1, off sc0 sc1" : "=v"(w3) : "v"(pp + 12) : "memory");
                asm volatile("s_waitcnt vmcnt(0)"
                             : "+v"(w0), "+v"(w1), "+v"(w2), "+v"(w3) :: "memory");
                int ok = 1;
                #pragma unroll
                for (int ee = 0; ee < 4; ++ee) {
                    ok &= ((w0[ee] >> 16) == ttag);
                    ok &= ((w1[ee] >> 16) == ttag);
                    ok &= ((w2[ee] >> 16) == ttag);
                    ok &= ((w3[ee] >> 16) == ttag);
                }
                if (__all(ok) || ++guard > 100000) break;
            }
            #pragma unroll
            for (int ee = 0; ee < 4; ++ee) {
                v0[ee]     = (short)(w0[ee] & 0xffffu);
                v0[4 + ee] = (short)(w1[ee] & 0xffffu);
                v1[ee]     = (short)(w2[ee] & 0xffffu);
                v1[4 + ee] = (short)(w3[ee] & 0xffffu);
            }
        }
        {
            int cg0 = lane * 2;
            char* base = (char*)&hA[s & 1][0] + sn * 2048;
            *(short8*)(base + (((unsigned)(cg0       ^ sn)) << 4)) = v0;
            *(short8*)(base + (((unsigned)((cg0 + 1) ^ sn)) << 4)) = v1;
        }
        __syncthreads();   // the ONLY barrier per step (stage -> MFMA, same parity buffer)

        // ---- recurrent MFMA: M=16 (rows 8..15 broadcast-duplicate 0..7) x N=16 x K=1024 ----
        f32x4 acc0 = {0.f,0.f,0.f,0.f}, acc1 = {0.f,0.f,0.f,0.f};
        {
            const int row = lane & 15;
            const unsigned rsw = (unsigned)(row & 7);
            // rows 8..15 read the SAME addresses as rows 0..7 -> LDS broadcast (free)
            const char* base = (const char*)&hA[s & 1][0] + (row & 7) * 2048;
            #pragma unroll
            for (int kb = 0; kb < 32; kb += 2) {
                int cgA = kb * 4 + kg;
                short8 a0 = *(const short8*)(base + (((unsigned)(cgA       ^ rsw)) << 4));
                short8 a1 = *(const short8*)(base + (((unsigned)((cgA + 4) ^ rsw)) << 4));
                acc0 = __builtin_amdgcn_mfma_f32_16x16x32_bf16(a0, bfr[kb],     acc0, 0, 0, 0);
                acc1 = __builtin_amdgcn_mfma_f32_16x16x32_bf16(a1, bfr[kb + 1], acc1, 0, 0, 0);
            }
            #pragma unroll
            for (int r = 0; r < 4; ++r) acc0[r] += acc1[r];
        }
        // ---- wave-local gate gather: 4 shuffle rounds (no LDS, no barrier) ----
        float iv = 0.f, fv = 0.f, gv = 0.f, ov = 0.f;
        #pragma unroll
        for (int j = 0; j < 4; ++j) {
            int sel = (q + j) & 3;
            float sv = (sel == 0) ? acc0[0] : (sel == 1) ? acc0[1]
                     : (sel == 2) ? acc0[2] : acc0[3];
            int src = (lane & ~3) | ((q - j) & 3);
            float rv = __shfl(sv, src, 64);
            int g = (q - j) & 3;
            iv = (g == 0) ? rv : iv;
            fv = (g == 1) ? rv : fv;
            gv = (g == 2) ? rv : gv;
            ov = (g == 3) ? rv : ov;
        }
        // ---- pointwise (lanes < 32 hold the 8 real rows x this wave's 4 units) ----
        if (lane < 32) {
            float ivv = iv + h2f(xi)  + bi;
            float fvv = fv + h2f(xf)  + bfv;
            float gvv = gv + h2f(xgv) + bg;
            float ovv = ov + h2f(xo)  + bov;
            ivv = 1.f / (1.f + __expf(-ivv));
            fvv = 1.f / (1.f + __expf(-fvv));
            ovv = 1.f / (1.f + __expf(-ovv));
            float eg = __expf(2.f * gvv);
            gvv = 1.f - 2.f / (eg + 1.f);
            creg = fvv * creg + ivv * gvv;
            float ec = __expf(2.f * creg);
            float hh = ovv * (1.f - 2.f / (ec + 1.f));
            unsigned short hb = f2bf(hh);
            int ng = G * 8 + nloc;
            if (s == TCH - 1) {
                hcan[((size_t)ng << 10) + jg] = hb;    // plain: next launch reads it
                cws[((size_t)ng << 10) + jg] = creg;
            } else {
                unsigned int wv = (((nonce6 << 10) | ((unsigned)(t + 1) & 1023u)) << 16)
                                  | (unsigned int)hb;
                unsigned int* hp = hx + ((size_t)(((t + 1) & 1) * 8 + G)) * 8192
                                      + nloc * 1024 + jg;
                asm volatile("global_store_dword %0, %1, off sc0 sc1"
                             :: "v"(hp), "v"(wv) : "memory");
            }
            y[((size_t)ng << 19) + ((size_t)t << 10) + jg] = hh;
        }
    }
}

extern "C" void kernel_launch(void* const* d_in, const int* in_sizes, int n_in,
                              void* d_out, int out_size, void* d_ws, size_t ws_size,
                              hipStream_t stream) {
    const float* x   = (const float*)d_in[0];
    const float* wih = (const float*)d_in[1];
    const float* whh = (const float*)d_in[2];
    const float* bih = (const float*)d_in[3];
    const float* bhh = (const float*)d_in[4];
    float* y = (float*)d_out;

    char* ws = (char*)d_ws;
    unsigned short* Whh_bf = (unsigned short*)ws;                           // 8 MiB
    unsigned short* Wih_bf = (unsigned short*)(ws + ((size_t)8 << 20));     // 8 MiB
    unsigned short* xgc    = (unsigned short*)(ws + ((size_t)16 << 20));    // 64 MiB (f16)
    char* SB               = ws + ((size_t)80 << 20);
    float* biasc           = (float*)SB;                                    // 16 KiB
    char* zb               = SB + (16u << 10);
    unsigned short* hcan   = (unsigned short*)zb;                           // 128 KiB
    float* cws             = (float*)(zb + (128u << 10));                   // 256 KiB
    unsigned int* hx       = (unsigned int*)(zb + (384u << 10));            // 512 KiB
    unsigned int* nonce    = (unsigned int*)(zb + (896u << 10));            // 4 B (NOT zeroed)
    const int nz = (896 << 10) / 4;
    if (ws_size < ((size_t)81 << 20)) return;

    hipLaunchKernelGGL(cvt_mat, dim3(2048), dim3(256), 0, stream, whh, Whh_bf, G4 * HID / 8);
    hipLaunchKernelGGL(cvt_mat, dim3(2048), dim3(256), 0, stream, wih, Wih_bf, G4 * HID / 8);
    hipLaunchKernelGGL(init_kernel, dim3(896), dim3(256), 0, stream,
                       bih, bhh, biasc, (unsigned int*)zb, nz, nonce);

    for (int chk = 0; chk < NCH; ++chk) {
        int t0 = chk * TCH;
        hipLaunchKernelGGL(xg_gemm, dim3(2048), dim3(256), 0, stream, x, Wih_bf, xgc, t0);
        void* args[] = {(void*)&Whh_bf, (void*)&xgc, (void*)&biasc, (void*)&hcan,
                        (void*)&hx, (void*)&cws, (void*)&nonce, (void*)&y, (void*)&t0};
        hipLaunchCooperativeKernel((const void*)lstm_persist, dim3(NWG), dim3(512),
                                   args, 0, stream);
    }
}

// Round 14
// 2194.090 us; speedup vs baseline: 1.2215x; 1.2215x over previous
//
#include <hip/hip_runtime.h>

#define HID 1024
#define G4 4096
#define TCH 128
#define NCH 4
#define NWG 256

typedef short short8 __attribute__((ext_vector_type(8)));
typedef float f32x4 __attribute__((ext_vector_type(4)));
typedef unsigned int u32x4 __attribute__((ext_vector_type(4)));

static __device__ __forceinline__ unsigned short f2bf(float f) {
    unsigned int u = __builtin_bit_cast(unsigned int, f);
    u += 0x7fffu + ((u >> 16) & 1u);
    return (unsigned short)(u >> 16);
}
static __device__ __forceinline__ unsigned short f2h(float v) {
    _Float16 h = (_Float16)v;
    return __builtin_bit_cast(unsigned short, h);
}
static __device__ __forceinline__ float h2f(unsigned short u) {
    return (float)__builtin_bit_cast(_Float16, u);
}

// fp32 -> bf16 bulk convert (n8 groups of 8)
__global__ void cvt_mat(const float* __restrict__ src, unsigned short* __restrict__ dst, int n8) {
    int idx = blockIdx.x * blockDim.x + threadIdx.x;
    if (idx >= n8) return;
    const float* s = src + (size_t)idx * 8;
    float4 a = *(const float4*)s;
    float4 b = *(const float4*)(s + 4);
    short8 v;
    v[0]=(short)f2bf(a.x); v[1]=(short)f2bf(a.y); v[2]=(short)f2bf(a.z); v[3]=(short)f2bf(a.w);
    v[4]=(short)f2bf(b.x); v[5]=(short)f2bf(b.y); v[6]=(short)f2bf(b.z); v[7]=(short)f2bf(b.w);
    *(short8*)(dst + (size_t)idx * 8) = v;
}

// x chunk (N,T,D slice) f32 -> xbc [tl*64+n][d] bf16 (fast path only)
__global__ void cvt_xb(const float* __restrict__ x, unsigned short* __restrict__ xbc, int t0) {
    int idx = blockIdx.x * blockDim.x + threadIdx.x;   // 1M threads
    int d = (idx & 127) * 8;
    int m = idx >> 7;                // 0..8191
    int tl = m >> 6, n = m & 63;
    const float* sp = x + ((size_t)n * 512 + (size_t)(t0 + tl)) * 1024 + d;
    float4 a = *(const float4*)sp;
    float4 b = *(const float4*)(sp + 4);
    short8 v;
    v[0]=(short)f2bf(a.x); v[1]=(short)f2bf(a.y); v[2]=(short)f2bf(a.z); v[3]=(short)f2bf(a.w);
    v[4]=(short)f2bf(b.x); v[5]=(short)f2bf(b.y); v[6]=(short)f2bf(b.z); v[7]=(short)f2bf(b.w);
    *(short8*)(xbc + (size_t)m * 1024 + d) = v;
}

// zero state region (hcan, cws, hx), combine biases, bump per-replay nonce
__global__ void init_kernel(const float* __restrict__ bih, const float* __restrict__ bhh,
                            float* __restrict__ biasc, unsigned int* __restrict__ zbase,
                            int nz, unsigned int* __restrict__ nonce) {
    int i = blockIdx.x * blockDim.x + threadIdx.x;
    if (i < nz) zbase[i] = 0u;
    if (i < G4) biasc[i] = bih[i] + bhh[i];
    if (i == 0) nonce[0] = nonce[0] + 1u;
}

// xg[m][g] = sum_k A[m][k]*Wih[g][k]; output f16 bits. SLOW path: A from f32 x.
__global__ __launch_bounds__(256) void xg_gemm(
    const float* __restrict__ x,            // [64][512][1024] fp32
    const unsigned short* __restrict__ wb,  // Wih_bf [4096][1024]
    unsigned short* __restrict__ xg,        // [TCH*64][4096] f16 chunk
    int t0) {
    __shared__ unsigned short Al[128][72];
    __shared__ unsigned short Bl[128][72];
    const int tid = threadIdx.x, w = tid >> 6, lane = tid & 63;
    const int bm = blockIdx.x >> 5, bn = blockIdx.x & 31;
    const int wr = w >> 1, wc = w & 1;
    const int fr = lane & 15, kg = lane >> 4;
    f32x4 acc[4][4];
    #pragma unroll
    for (int i = 0; i < 4; ++i)
        #pragma unroll
        for (int j = 0; j < 4; ++j) acc[i][j] = (f32x4){0.f,0.f,0.f,0.f};

    for (int kt = 0; kt < 16; ++kt) {
        __syncthreads();
        #pragma unroll
        for (int c = 0; c < 4; ++c) {
            int idx = c * 256 + tid;
            int row = idx >> 3, co = (idx & 7) * 8;
            int m = bm * 128 + row;
            const float* sp = x + ((size_t)(m & 63) * 512 + (size_t)(t0 + (m >> 6))) * 1024
                                + kt * 64 + co;
            float4 a = *(const float4*)sp;
            float4 b = *(const float4*)(sp + 4);
            short8 v;
            v[0]=(short)f2bf(a.x); v[1]=(short)f2bf(a.y); v[2]=(short)f2bf(a.z); v[3]=(short)f2bf(a.w);
            v[4]=(short)f2bf(b.x); v[5]=(short)f2bf(b.y); v[6]=(short)f2bf(b.z); v[7]=(short)f2bf(b.w);
            *(short8*)&Al[row][co] = v;
            *(short8*)&Bl[row][co] = *(const short8*)(wb + (size_t)(bn * 128 + row) * 1024 + kt * 64 + co);
        }
        __syncthreads();
        #pragma unroll
        for (int kb = 0; kb < 2; ++kb) {
            short8 af[4], bf_[4];
            #pragma unroll
            for (int mi = 0; mi < 4; ++mi)
                af[mi] = *(const short8*)&Al[wr*64 + mi*16 + fr][kb*32 + kg*8];
            #pragma unroll
            for (int ni = 0; ni < 4; ++ni)
                bf_[ni] = *(const short8*)&Bl[wc*64 + ni*16 + fr][kb*32 + kg*8];
            #pragma unroll
            for (int mi = 0; mi < 4; ++mi)
                #pragma unroll
                for (int ni = 0; ni < 4; ++ni)
                    acc[mi][ni] = __builtin_amdgcn_mfma_f32_16x16x32_bf16(af[mi], bf_[ni], acc[mi][ni], 0, 0, 0);
        }
    }
    #pragma unroll
    for (int mi = 0; mi < 4; ++mi)
        #pragma unroll
        for (int ni = 0; ni < 4; ++ni)
            #pragma unroll
            for (int r = 0; r < 4; ++r) {
                int row = bm*128 + wr*64 + mi*16 + kg*4 + r;
                int col = bn*128 + wc*64 + ni*16 + fr;
                xg[(size_t)row * 4096 + col] = f2h(acc[mi][ni][r]);
            }
}

// FAST path: identical math, A staged as bf16 short8 from pre-converted xbc
// (halved A traffic, no in-loop f32->bf16 VALU). xg bits identical to slow path.
__global__ __launch_bounds__(256) void xg_gemm_bf(
    const unsigned short* __restrict__ xbc, // [8192][1024] bf16 chunk A
    const unsigned short* __restrict__ wb,  // Wih_bf [4096][1024]
    unsigned short* __restrict__ xg) {      // [TCH*64][4096] f16 chunk
    __shared__ unsigned short Al[128][72];
    __shared__ unsigned short Bl[128][72];
    const int tid = threadIdx.x, w = tid >> 6, lane = tid & 63;
    const int bm = blockIdx.x >> 5, bn = blockIdx.x & 31;
    const int wr = w >> 1, wc = w & 1;
    const int fr = lane & 15, kg = lane >> 4;
    f32x4 acc[4][4];
    #pragma unroll
    for (int i = 0; i < 4; ++i)
        #pragma unroll
        for (int j = 0; j < 4; ++j) acc[i][j] = (f32x4){0.f,0.f,0.f,0.f};

    for (int kt = 0; kt < 16; ++kt) {
        __syncthreads();
        #pragma unroll
        for (int c = 0; c < 4; ++c) {
            int idx = c * 256 + tid;
            int row = idx >> 3, co = (idx & 7) * 8;
            *(short8*)&Al[row][co] = *(const short8*)(xbc + (size_t)(bm * 128 + row) * 1024 + kt * 64 + co);
            *(short8*)&Bl[row][co] = *(const short8*)(wb  + (size_t)(bn * 128 + row) * 1024 + kt * 64 + co);
        }
        __syncthreads();
        #pragma unroll
        for (int kb = 0; kb < 2; ++kb) {
            short8 af[4], bf_[4];
            #pragma unroll
            for (int mi = 0; mi < 4; ++mi)
                af[mi] = *(const short8*)&Al[wr*64 + mi*16 + fr][kb*32 + kg*8];
            #pragma unroll
            for (int ni = 0; ni < 4; ++ni)
                bf_[ni] = *(const short8*)&Bl[wc*64 + ni*16 + fr][kb*32 + kg*8];
            #pragma unroll
            for (int mi = 0; mi < 4; ++mi)
                #pragma unroll
                for (int ni = 0; ni < 4; ++ni)
                    acc[mi][ni] = __builtin_amdgcn_mfma_f32_16x16x32_bf16(af[mi], bf_[ni], acc[mi][ni], 0, 0, 0);
        }
    }
    #pragma unroll
    for (int mi = 0; mi < 4; ++mi)
        #pragma unroll
        for (int ni = 0; ni < 4; ++ni)
            #pragma unroll
            for (int r = 0; r < 4; ++r) {
                int row = bm*128 + wr*64 + mi*16 + kg*4 + r;
                int col = bn*128 + wc*64 + ni*16 + fr;
                xg[(size_t)row * 4096 + col] = f2h(acc[mi][ni][r]);
            }
}

// Persistent LSTM chunk (128 steps). R13 structure with three chain cuts:
//  L1: poll element mapping lane -> elems [8L,+8) and [512+8L,+8); LDS stage writes
//      slots lane^sn and 64+(lane^sn): each write insn spans all 8 bank groups
//      (8-way floor, was 16-way). Read swizzle (slot^rsw) unchanged/consistent.
//  L2: MFMA ds_read addresses hoisted: addr(kb) = base + ((kg^rsw)<<4) [^64] + 64*kb
//      (exact since kb even => kb*4 has no bits 0..2) -> all reads base+const.
//  L3: OR-reduced tag check.
__global__ __launch_bounds__(512, 2) void lstm_persist(
    const unsigned short* __restrict__ whh,   // Whh_bf [4096][1024]
    const unsigned short* __restrict__ xg,    // [TCH*64][4096] f16 bits
    const float* __restrict__ biasc,          // [4096]
    unsigned short* __restrict__ hcan,        // [64][1024] bf16 chunk-boundary h
    unsigned int* __restrict__ hx,            // [2 par][8 G][8][1024] u32 tagged h
    float* __restrict__ cws,                  // [64][1024] chunk-boundary c
    const unsigned int* __restrict__ nonce,   // [1]
    float* __restrict__ y, int t0) {
    __shared__ unsigned short hA[2][8192];    // [par][8][1024] bf16, XOR-swizzled

    const int tid = threadIdx.x, w = tid >> 6, lane = tid & 63;
    const int G = (int)(blockIdx.x >> 5);
    const int l = (int)(blockIdx.x & 31);

    const int c  = lane & 15, kg = lane >> 4;
    const int q  = c & 3;                  // gate type of this lane's B column
    const int e  = c >> 2;                 // unit-within-4 of this lane's B column
    const int jg = l * 32 + w * 4 + e;     // global hidden unit (output lanes <32)
    const int nloc = kg * 4 + q;           // group-local batch row (output lanes <32)
    const unsigned int nonce6 = nonce[0] & 63u;

    short8 bfr[32];   // Whh row (q*1024 + jg), K=1024
    {
        const unsigned short* wp = whh + ((size_t)(q * 1024 + jg) << 10) + kg * 8;
        #pragma unroll
        for (int kb = 0; kb < 32; ++kb) bfr[kb] = *(const short8*)(wp + kb * 32);
    }
    const float bi = biasc[jg],        bfv = biasc[1024 + jg];
    const float bg = biasc[2048 + jg], bov = biasc[3072 + jg];

    float creg = 0.f;
    if (lane < 32) creg = cws[((size_t)(G * 8 + nloc) << 10) + jg];
    __syncthreads();

    const int sn = w;   // staging batch row 0..7 (one per wave)
    const int row = lane & 15;
    const unsigned rsw = (unsigned)(row & 7);
    const unsigned b0off = ((unsigned)(kg) ^ rsw) << 4;

    for (int s = 0; s < TCH; ++s) {
        const int t = t0 + s;
        // ---- xg prefetch (4 scalar loads; complete under the poll) ----
        unsigned short xi = 0, xf = 0, xgv = 0, xo = 0;
        if (lane < 32) {
            const unsigned short* xp = xg + ((size_t)(s * 64 + G * 8 + nloc) << 12) + jg;
            xi = xp[0]; xf = xp[1024]; xgv = xp[2048]; xo = xp[3072];
        }
        // ---- acquire h(t) row sn: lane holds elems [8L,+8) and [512+8L,+8) ----
        short8 v0, v1;
        if (s == 0) {
            const unsigned short* hp = hcan + ((size_t)(G * 8 + sn) << 10);
            v0 = *(const short8*)(hp + lane * 8);
            v1 = *(const short8*)(hp + 512 + lane * 8);
        } else {
            const unsigned int* pp = hx + ((size_t)((t & 1) * 8 + G)) * 8192 + sn * 1024 + lane * 8;
            const unsigned int xm = ((nonce6 << 10) | ((unsigned)t & 1023u)) << 16;
            u32x4 w0, w1, w2, w3;
            int guard = 0;
            while (true) {
                asm volatile("global_load_dwordx4 %0, %1, off sc0 sc1" : "=v"(w0) : "v"(pp)       : "memory");
                asm volatile("global_load_dwordx4 %0, %1, off sc0 sc1" : "=v"(w1) : "v"(pp + 4)   : "memory");
                asm volatile("global_load_dwordx4 %0, %1, off sc0 sc1" : "=v"(w2) : "v"(pp + 512) : "memory");
                asm volatile("global_load_dwordx4 %0, %1, off sc0 sc1" : "=v"(w3) : "v"(pp + 516) : "memory");
                asm volatile("s_waitcnt vmcnt(0)"
                             : "+v"(w0), "+v"(w1), "+v"(w2), "+v"(w3) :: "memory");
                unsigned int accb = 0;
                #pragma unroll
                for (int ee = 0; ee < 4; ++ee)
                    accb |= (w0[ee] ^ xm) | (w1[ee] ^ xm) | (w2[ee] ^ xm) | (w3[ee] ^ xm);
                if (__all((int)((accb >> 16) == 0u)) || ++guard > 100000) break;
            }
            #pragma unroll
            for (int ee = 0; ee < 4; ++ee) {
                v0[ee]     = (short)(w0[ee] & 0xffffu);
                v0[4 + ee] = (short)(w1[ee] & 0xffffu);
                v1[ee]     = (short)(w2[ee] & 0xffffu);
                v1[4 + ee] = (short)(w3[ee] & 0xffffu);
            }
        }
        {   // stage: slots lane^sn (elems 8L..) and 64+(lane^sn) (elems 512+8L..)
            char* base = (char*)&hA[s & 1][0] + sn * 2048 + (((unsigned)(lane ^ sn)) << 4);
            *(short8*)(base)        = v0;
            *(short8*)(base + 1024) = v1;
        }
        __syncthreads();   // the ONLY barrier per step

        // ---- recurrent MFMA: hoisted base addressing, immediate offsets ----
        f32x4 acc0 = {0.f,0.f,0.f,0.f}, acc1 = {0.f,0.f,0.f,0.f};
        {
            const char* bas = (const char*)&hA[s & 1][0] + (row & 7) * 2048;
            const char* p0 = bas + b0off;
            const char* p1 = bas + (b0off ^ 64u);
            #pragma unroll
            for (int kb = 0; kb < 32; kb += 2) {
                short8 a0 = *(const short8*)(p0 + kb * 64);
                short8 a1 = *(const short8*)(p1 + kb * 64);
                acc0 = __builtin_amdgcn_mfma_f32_16x16x32_bf16(a0, bfr[kb],     acc0, 0, 0, 0);
                acc1 = __builtin_amdgcn_mfma_f32_16x16x32_bf16(a1, bfr[kb + 1], acc1, 0, 0, 0);
            }
            #pragma unroll
            for (int r = 0; r < 4; ++r) acc0[r] += acc1[r];
        }
        // ---- wave-local gate gather: 4 shuffle rounds (no LDS, no barrier) ----
        float iv = 0.f, fv = 0.f, gv = 0.f, ov = 0.f;
        #pragma unroll
        for (int j = 0; j < 4; ++j) {
            int sel = (q + j) & 3;
            float sv = (sel == 0) ? acc0[0] : (sel == 1) ? acc0[1]
                     : (sel == 2) ? acc0[2] : acc0[3];
            int src = (lane & ~3) | ((q - j) & 3);
            float rv = __shfl(sv, src, 64);
            int g = (q - j) & 3;
            iv = (g == 0) ? rv : iv;
            fv = (g == 1) ? rv : fv;
            gv = (g == 2) ? rv : gv;
            ov = (g == 3) ? rv : ov;
        }
        // ---- pointwise (lanes < 32 hold the 8 real rows x this wave's 4 units) ----
        if (lane < 32) {
            float ivv = iv + h2f(xi)  + bi;
            float fvv = fv + h2f(xf)  + bfv;
            float gvv = gv + h2f(xgv) + bg;
            float ovv = ov + h2f(xo)  + bov;
            ivv = 1.f / (1.f + __expf(-ivv));
            fvv = 1.f / (1.f + __expf(-fvv));
            ovv = 1.f / (1.f + __expf(-ovv));
            float eg = __expf(2.f * gvv);
            gvv = 1.f - 2.f / (eg + 1.f);
            creg = fvv * creg + ivv * gvv;
            float ec = __expf(2.f * creg);
            float hh = ovv * (1.f - 2.f / (ec + 1.f));
            unsigned short hb = f2bf(hh);
            int ng = G * 8 + nloc;
            if (s == TCH - 1) {
                hcan[((size_t)ng << 10) + jg] = hb;    // plain: next launch reads it
                cws[((size_t)ng << 10) + jg] = creg;
            } else {
                unsigned int wv = (((nonce6 << 10) | ((unsigned)(t + 1) & 1023u)) << 16)
                                  | (unsigned int)hb;
                unsigned int* hp = hx + ((size_t)(((t + 1) & 1) * 8 + G)) * 8192
                                      + nloc * 1024 + jg;
                asm volatile("global_store_dword %0, %1, off sc0 sc1"
                             :: "v"(hp), "v"(wv) : "memory");
            }
            y[((size_t)ng << 19) + ((size_t)t << 10) + jg] = hh;
        }
    }
}

extern "C" void kernel_launch(void* const* d_in, const int* in_sizes, int n_in,
                              void* d_out, int out_size, void* d_ws, size_t ws_size,
                              hipStream_t stream) {
    const float* x   = (const float*)d_in[0];
    const float* wih = (const float*)d_in[1];
    const float* whh = (const float*)d_in[2];
    const float* bih = (const float*)d_in[3];
    const float* bhh = (const float*)d_in[4];
    float* y = (float*)d_out;

    char* ws = (char*)d_ws;
    unsigned short* Whh_bf = (unsigned short*)ws;                           // 8 MiB
    unsigned short* Wih_bf = (unsigned short*)(ws + ((size_t)8 << 20));     // 8 MiB
    unsigned short* xgc    = (unsigned short*)(ws + ((size_t)16 << 20));    // 64 MiB (f16)
    char* SB               = ws + ((size_t)80 << 20);
    float* biasc           = (float*)SB;                                    // 16 KiB
    char* zb               = SB + (16u << 10);
    unsigned short* hcan   = (unsigned short*)zb;                           // 128 KiB
    float* cws             = (float*)(zb + (128u << 10));                   // 256 KiB
    unsigned int* hx       = (unsigned int*)(zb + (384u << 10));            // 512 KiB
    unsigned int* nonce    = (unsigned int*)(zb + (896u << 10));            // 4 B (NOT zeroed)
    unsigned short* xbc    = (unsigned short*)(ws + ((size_t)81 << 20));    // 16 MiB (fast path)
    const int nz = (896 << 10) / 4;
    if (ws_size < ((size_t)81 << 20)) return;
    const bool fast = ws_size >= ((size_t)98 << 20);

    hipLaunchKernelGGL(cvt_mat, dim3(2048), dim3(256), 0, stream, whh, Whh_bf, G4 * HID / 8);
    hipLaunchKernelGGL(cvt_mat, dim3(2048), dim3(256), 0, stream, wih, Wih_bf, G4 * HID / 8);
    hipLaunchKernelGGL(init_kernel, dim3(896), dim3(256), 0, stream,
                       bih, bhh, biasc, (unsigned int*)zb, nz, nonce);

    for (int chk = 0; chk < NCH; ++chk) {
        int t0 = chk * TCH;
        if (fast) {
            hipLaunchKernelGGL(cvt_xb, dim3(4096), dim3(256), 0, stream, x, xbc, t0);
            hipLaunchKernelGGL(xg_gemm_bf, dim3(2048), dim3(256), 0, stream, xbc, Wih_bf, xgc);
        } else {
            hipLaunchKernelGGL(xg_gemm, dim3(2048), dim3(256), 0, stream, x, Wih_bf, xgc, t0);
        }
        void* args[] = {(void*)&Whh_bf, (void*)&xgc, (void*)&biasc, (void*)&hcan,
                        (void*)&hx, (void*)&cws, (void*)&nonce, (void*)&y, (void*)&t0};
        hipLaunchCooperativeKernel((const void*)lstm_persist, dim3(NWG), dim3(512),
                                   args, 0, stream);
    }
}

// Round 15
// 2182.450 us; speedup vs baseline: 1.2280x; 1.0053x over previous
//
#include <hip/hip_runtime.h>

#define HID 1024
#define G4 4096
#define TCH 128
#define NCH 4
#define NWG 256

typedef short short8 __attribute__((ext_vector_type(8)));
typedef float f32x4 __attribute__((ext_vector_type(4)));
typedef unsigned int u32x4 __attribute__((ext_vector_type(4)));

static __device__ __forceinline__ unsigned short f2bf(float f) {
    unsigned int u = __builtin_bit_cast(unsigned int, f);
    u += 0x7fffu + ((u >> 16) & 1u);
    return (unsigned short)(u >> 16);
}
static __device__ __forceinline__ unsigned short f2h(float v) {
    _Float16 h = (_Float16)v;
    return __builtin_bit_cast(unsigned short, h);
}
static __device__ __forceinline__ float h2f(unsigned short u) {
    return (float)__builtin_bit_cast(_Float16, u);
}

// fused fp32 -> bf16 convert for BOTH weight matrices (one launch)
__global__ void cvt_w2(const float* __restrict__ whh, const float* __restrict__ wih,
                       unsigned short* __restrict__ whh_bf, unsigned short* __restrict__ wih_bf) {
    int idx = blockIdx.x * blockDim.x + threadIdx.x;   // 1M threads, 512K groups each
    const float* src;
    unsigned short* dst;
    if (idx < 524288) { src = whh + (size_t)idx * 8; dst = whh_bf + (size_t)idx * 8; }
    else { int k = idx - 524288; src = wih + (size_t)k * 8; dst = wih_bf + (size_t)k * 8; }
    float4 a = *(const float4*)src;
    float4 b = *(const float4*)(src + 4);
    short8 v;
    v[0]=(short)f2bf(a.x); v[1]=(short)f2bf(a.y); v[2]=(short)f2bf(a.z); v[3]=(short)f2bf(a.w);
    v[4]=(short)f2bf(b.x); v[5]=(short)f2bf(b.y); v[6]=(short)f2bf(b.z); v[7]=(short)f2bf(b.w);
    *(short8*)dst = v;
}

// x chunk (N,T,D slice) f32 -> xbc [tl*64+n][d] bf16 (fast path only)
__global__ void cvt_xb(const float* __restrict__ x, unsigned short* __restrict__ xbc, int t0) {
    int idx = blockIdx.x * blockDim.x + threadIdx.x;   // 1M threads
    int d = (idx & 127) * 8;
    int m = idx >> 7;                // 0..8191
    int tl = m >> 6, n = m & 63;
    const float* sp = x + ((size_t)n * 512 + (size_t)(t0 + tl)) * 1024 + d;
    float4 a = *(const float4*)sp;
    float4 b = *(const float4*)(sp + 4);
    short8 v;
    v[0]=(short)f2bf(a.x); v[1]=(short)f2bf(a.y); v[2]=(short)f2bf(a.z); v[3]=(short)f2bf(a.w);
    v[4]=(short)f2bf(b.x); v[5]=(short)f2bf(b.y); v[6]=(short)f2bf(b.z); v[7]=(short)f2bf(b.w);
    *(short8*)(xbc + (size_t)m * 1024 + d) = v;
}

// zero state region (hcan, cws, hx), combine biases, bump per-replay nonce
__global__ void init_kernel(const float* __restrict__ bih, const float* __restrict__ bhh,
                            float* __restrict__ biasc, unsigned int* __restrict__ zbase,
                            int nz, unsigned int* __restrict__ nonce) {
    int i = blockIdx.x * blockDim.x + threadIdx.x;
    if (i < nz) zbase[i] = 0u;
    if (i < G4) biasc[i] = bih[i] + bhh[i];
    if (i == 0) nonce[0] = nonce[0] + 1u;
}

// xg[m][g] = sum_k A[m][k]*Wih[g][k]; output f16 bits. SLOW path: A from f32 x.
__global__ __launch_bounds__(256) void xg_gemm(
    const float* __restrict__ x,            // [64][512][1024] fp32
    const unsigned short* __restrict__ wb,  // Wih_bf [4096][1024]
    unsigned short* __restrict__ xg,        // [TCH*64][4096] f16 chunk
    int t0) {
    __shared__ unsigned short Al[128][72];
    __shared__ unsigned short Bl[128][72];
    const int tid = threadIdx.x, w = tid >> 6, lane = tid & 63;
    const int bm = blockIdx.x >> 5, bn = blockIdx.x & 31;
    const int wr = w >> 1, wc = w & 1;
    const int fr = lane & 15, kg = lane >> 4;
    f32x4 acc[4][4];
    #pragma unroll
    for (int i = 0; i < 4; ++i)
        #pragma unroll
        for (int j = 0; j < 4; ++j) acc[i][j] = (f32x4){0.f,0.f,0.f,0.f};

    for (int kt = 0; kt < 16; ++kt) {
        __syncthreads();
        #pragma unroll
        for (int c = 0; c < 4; ++c) {
            int idx = c * 256 + tid;
            int row = idx >> 3, co = (idx & 7) * 8;
            int m = bm * 128 + row;
            const float* sp = x + ((size_t)(m & 63) * 512 + (size_t)(t0 + (m >> 6))) * 1024
                                + kt * 64 + co;
            float4 a = *(const float4*)sp;
            float4 b = *(const float4*)(sp + 4);
            short8 v;
            v[0]=(short)f2bf(a.x); v[1]=(short)f2bf(a.y); v[2]=(short)f2bf(a.z); v[3]=(short)f2bf(a.w);
            v[4]=(short)f2bf(b.x); v[5]=(short)f2bf(b.y); v[6]=(short)f2bf(b.z); v[7]=(short)f2bf(b.w);
            *(short8*)&Al[row][co] = v;
            *(short8*)&Bl[row][co] = *(const short8*)(wb + (size_t)(bn * 128 + row) * 1024 + kt * 64 + co);
        }
        __syncthreads();
        #pragma unroll
        for (int kb = 0; kb < 2; ++kb) {
            short8 af[4], bf_[4];
            #pragma unroll
            for (int mi = 0; mi < 4; ++mi)
                af[mi] = *(const short8*)&Al[wr*64 + mi*16 + fr][kb*32 + kg*8];
            #pragma unroll
            for (int ni = 0; ni < 4; ++ni)
                bf_[ni] = *(const short8*)&Bl[wc*64 + ni*16 + fr][kb*32 + kg*8];
            #pragma unroll
            for (int mi = 0; mi < 4; ++mi)
                #pragma unroll
                for (int ni = 0; ni < 4; ++ni)
                    acc[mi][ni] = __builtin_amdgcn_mfma_f32_16x16x32_bf16(af[mi], bf_[ni], acc[mi][ni], 0, 0, 0);
        }
    }
    #pragma unroll
    for (int mi = 0; mi < 4; ++mi)
        #pragma unroll
        for (int ni = 0; ni < 4; ++ni)
            #pragma unroll
            for (int r = 0; r < 4; ++r) {
                int row = bm*128 + wr*64 + mi*16 + kg*4 + r;
                int col = bn*128 + wc*64 + ni*16 + fr;
                xg[(size_t)row * 4096 + col] = f2h(acc[mi][ni][r]);
            }
}

// FAST path: identical math, A staged as bf16 short8 from pre-converted xbc.
__global__ __launch_bounds__(256) void xg_gemm_bf(
    const unsigned short* __restrict__ xbc, // [8192][1024] bf16 chunk A
    const unsigned short* __restrict__ wb,  // Wih_bf [4096][1024]
    unsigned short* __restrict__ xg) {      // [TCH*64][4096] f16 chunk
    __shared__ unsigned short Al[128][72];
    __shared__ unsigned short Bl[128][72];
    const int tid = threadIdx.x, w = tid >> 6, lane = tid & 63;
    const int bm = blockIdx.x >> 5, bn = blockIdx.x & 31;
    const int wr = w >> 1, wc = w & 1;
    const int fr = lane & 15, kg = lane >> 4;
    f32x4 acc[4][4];
    #pragma unroll
    for (int i = 0; i < 4; ++i)
        #pragma unroll
        for (int j = 0; j < 4; ++j) acc[i][j] = (f32x4){0.f,0.f,0.f,0.f};

    for (int kt = 0; kt < 16; ++kt) {
        __syncthreads();
        #pragma unroll
        for (int c = 0; c < 4; ++c) {
            int idx = c * 256 + tid;
            int row = idx >> 3, co = (idx & 7) * 8;
            *(short8*)&Al[row][co] = *(const short8*)(xbc + (size_t)(bm * 128 + row) * 1024 + kt * 64 + co);
            *(short8*)&Bl[row][co] = *(const short8*)(wb  + (size_t)(bn * 128 + row) * 1024 + kt * 64 + co);
        }
        __syncthreads();
        #pragma unroll
        for (int kb = 0; kb < 2; ++kb) {
            short8 af[4], bf_[4];
            #pragma unroll
            for (int mi = 0; mi < 4; ++mi)
                af[mi] = *(const short8*)&Al[wr*64 + mi*16 + fr][kb*32 + kg*8];
            #pragma unroll
            for (int ni = 0; ni < 4; ++ni)
                bf_[ni] = *(const short8*)&Bl[wc*64 + ni*16 + fr][kb*32 + kg*8];
            #pragma unroll
            for (int mi = 0; mi < 4; ++mi)
                #pragma unroll
                for (int ni = 0; ni < 4; ++ni)
                    acc[mi][ni] = __builtin_amdgcn_mfma_f32_16x16x32_bf16(af[mi], bf_[ni], acc[mi][ni], 0, 0, 0);
        }
    }
    #pragma unroll
    for (int mi = 0; mi < 4; ++mi)
        #pragma unroll
        for (int ni = 0; ni < 4; ++ni)
            #pragma unroll
            for (int r = 0; r < 4; ++r) {
                int row = bm*128 + wr*64 + mi*16 + kg*4 + r;
                int col = bn*128 + wc*64 + ni*16 + fr;
                xg[(size_t)row * 4096 + col] = f2h(acc[mi][ni][r]);
            }
}

// Persistent LSTM chunk (128 steps). R14 structure; ONE change in the poll:
// SELECTIVE RETRY -- each dwordx4 quad has an ok-bit; once its 4 tags match it is
// latched in registers and never re-loaded. First iteration reads all 16 words
// (irreducible); retries re-read only the stale quads -> group-wide poll traffic
// per step drops from ~3x8MB to ~8MB + epsilon (IF$ coherent-path BW relief).
__global__ __launch_bounds__(512, 2) void lstm_persist(
    const unsigned short* __restrict__ whh,   // Whh_bf [4096][1024]
    const unsigned short* __restrict__ xg,    // [TCH*64][4096] f16 bits
    const float* __restrict__ biasc,          // [4096]
    unsigned short* __restrict__ hcan,        // [64][1024] bf16 chunk-boundary h
    unsigned int* __restrict__ hx,            // [2 par][8 G][8][1024] u32 tagged h
    float* __restrict__ cws,                  // [64][1024] chunk-boundary c
    const unsigned int* __restrict__ nonce,   // [1]
    float* __restrict__ y, int t0) {
    __shared__ unsigned short hA[2][8192];    // [par][8][1024] bf16, XOR-swizzled

    const int tid = threadIdx.x, w = tid >> 6, lane = tid & 63;
    const int G = (int)(blockIdx.x >> 5);
    const int l = (int)(blockIdx.x & 31);

    const int c  = lane & 15, kg = lane >> 4;
    const int q  = c & 3;                  // gate type of this lane's B column
    const int e  = c >> 2;                 // unit-within-4 of this lane's B column
    const int jg = l * 32 + w * 4 + e;     // global hidden unit (output lanes <32)
    const int nloc = kg * 4 + q;           // group-local batch row (output lanes <32)
    const unsigned int nonce6 = nonce[0] & 63u;

    short8 bfr[32];   // Whh row (q*1024 + jg), K=1024
    {
        const unsigned short* wp = whh + ((size_t)(q * 1024 + jg) << 10) + kg * 8;
        #pragma unroll
        for (int kb = 0; kb < 32; ++kb) bfr[kb] = *(const short8*)(wp + kb * 32);
    }
    const float bi = biasc[jg],        bfv = biasc[1024 + jg];
    const float bg = biasc[2048 + jg], bov = biasc[3072 + jg];

    float creg = 0.f;
    if (lane < 32) creg = cws[((size_t)(G * 8 + nloc) << 10) + jg];
    __syncthreads();

    const int sn = w;   // staging batch row 0..7 (one per wave)
    const int row = lane & 15;
    const unsigned rsw = (unsigned)(row & 7);
    const unsigned b0off = ((unsigned)(kg) ^ rsw) << 4;

    for (int s = 0; s < TCH; ++s) {
        const int t = t0 + s;
        // ---- xg prefetch (4 scalar loads; complete under the poll) ----
        unsigned short xi = 0, xf = 0, xgv = 0, xo = 0;
        if (lane < 32) {
            const unsigned short* xp = xg + ((size_t)(s * 64 + G * 8 + nloc) << 12) + jg;
            xi = xp[0]; xf = xp[1024]; xgv = xp[2048]; xo = xp[3072];
        }
        // ---- acquire h(t) row sn: selective-retry poll (re-read only stale quads) ----
        short8 v0, v1;
        if (s == 0) {
            const unsigned short* hp = hcan + ((size_t)(G * 8 + sn) << 10);
            v0 = *(const short8*)(hp + lane * 8);
            v1 = *(const short8*)(hp + 512 + lane * 8);
        } else {
            const unsigned int* pp = hx + ((size_t)((t & 1) * 8 + G)) * 8192 + sn * 1024 + lane * 8;
            const unsigned int xm = ((nonce6 << 10) | ((unsigned)t & 1023u)) << 16;
            u32x4 w0, w1, w2, w3;
            unsigned int okm = 0;   // bit k = quad k latched
            int guard = 0;
            while (true) {
                if (!(okm & 1u))
                    asm volatile("global_load_dwordx4 %0, %1, off sc0 sc1" : "=v"(w0) : "v"(pp)       : "memory");
                if (!(okm & 2u))
                    asm volatile("global_load_dwordx4 %0, %1, off sc0 sc1" : "=v"(w1) : "v"(pp + 4)   : "memory");
                if (!(okm & 4u))
                    asm volatile("global_load_dwordx4 %0, %1, off sc0 sc1" : "=v"(w2) : "v"(pp + 512) : "memory");
                if (!(okm & 8u))
                    asm volatile("global_load_dwordx4 %0, %1, off sc0 sc1" : "=v"(w3) : "v"(pp + 516) : "memory");
                asm volatile("s_waitcnt vmcnt(0)"
                             : "+v"(w0), "+v"(w1), "+v"(w2), "+v"(w3) :: "memory");
                unsigned int a0 = (w0[0]^xm)|(w0[1]^xm)|(w0[2]^xm)|(w0[3]^xm);
                unsigned int a1 = (w1[0]^xm)|(w1[1]^xm)|(w1[2]^xm)|(w1[3]^xm);
                unsigned int a2 = (w2[0]^xm)|(w2[1]^xm)|(w2[2]^xm)|(w2[3]^xm);
                unsigned int a3 = (w3[0]^xm)|(w3[1]^xm)|(w3[2]^xm)|(w3[3]^xm);
                okm |= ((a0 >> 16) == 0u) ? 1u : 0u;
                okm |= ((a1 >> 16) == 0u) ? 2u : 0u;
                okm |= ((a2 >> 16) == 0u) ? 4u : 0u;
                okm |= ((a3 >> 16) == 0u) ? 8u : 0u;
                if (__all((int)(okm == 15u)) || ++guard > 100000) break;
            }
            #pragma unroll
            for (int ee = 0; ee < 4; ++ee) {
                v0[ee]     = (short)(w0[ee] & 0xffffu);
                v0[4 + ee] = (short)(w1[ee] & 0xffffu);
                v1[ee]     = (short)(w2[ee] & 0xffffu);
                v1[4 + ee] = (short)(w3[ee] & 0xffffu);
            }
        }
        {   // stage: slots lane^sn (elems 8L..) and 64+(lane^sn) (elems 512+8L..)
            char* base = (char*)&hA[s & 1][0] + sn * 2048 + (((unsigned)(lane ^ sn)) << 4);
            *(short8*)(base)        = v0;
            *(short8*)(base + 1024) = v1;
        }
        __syncthreads();   // the ONLY barrier per step

        // ---- recurrent MFMA: hoisted base addressing, immediate offsets ----
        f32x4 acc0 = {0.f,0.f,0.f,0.f}, acc1 = {0.f,0.f,0.f,0.f};
        {
            const char* bas = (const char*)&hA[s & 1][0] + (row & 7) * 2048;
            const char* p0 = bas + b0off;
            const char* p1 = bas + (b0off ^ 64u);
            #pragma unroll
            for (int kb = 0; kb < 32; kb += 2) {
                short8 a0 = *(const short8*)(p0 + kb * 64);
                short8 a1 = *(const short8*)(p1 + kb * 64);
                acc0 = __builtin_amdgcn_mfma_f32_16x16x32_bf16(a0, bfr[kb],     acc0, 0, 0, 0);
                acc1 = __builtin_amdgcn_mfma_f32_16x16x32_bf16(a1, bfr[kb + 1], acc1, 0, 0, 0);
            }
            #pragma unroll
            for (int r = 0; r < 4; ++r) acc0[r] += acc1[r];
        }
        // ---- wave-local gate gather: 4 shuffle rounds (no LDS, no barrier) ----
        float iv = 0.f, fv = 0.f, gv = 0.f, ov = 0.f;
        #pragma unroll
        for (int j = 0; j < 4; ++j) {
            int sel = (q + j) & 3;
            float sv = (sel == 0) ? acc0[0] : (sel == 1) ? acc0[1]
                     : (sel == 2) ? acc0[2] : acc0[3];
            int src = (lane & ~3) | ((q - j) & 3);
            float rv = __shfl(sv, src, 64);
            int g = (q - j) & 3;
            iv = (g == 0) ? rv : iv;
            fv = (g == 1) ? rv : fv;
            gv = (g == 2) ? rv : gv;
            ov = (g == 3) ? rv : ov;
        }
        // ---- pointwise (lanes < 32 hold the 8 real rows x this wave's 4 units) ----
        if (lane < 32) {
            float ivv = iv + h2f(xi)  + bi;
            float fvv = fv + h2f(xf)  + bfv;
            float gvv = gv + h2f(xgv) + bg;
            float ovv = ov + h2f(xo)  + bov;
            ivv = 1.f / (1.f + __expf(-ivv));
            fvv = 1.f / (1.f + __expf(-fvv));
            ovv = 1.f / (1.f + __expf(-ovv));
            float eg = __expf(2.f * gvv);
            gvv = 1.f - 2.f / (eg + 1.f);
            creg = fvv * creg + ivv * gvv;
            float ec = __expf(2.f * creg);
            float hh = ovv * (1.f - 2.f / (ec + 1.f));
            unsigned short hb = f2bf(hh);
            int ng = G * 8 + nloc;
            if (s == TCH - 1) {
                hcan[((size_t)ng << 10) + jg] = hb;    // plain: next launch reads it
                cws[((size_t)ng << 10) + jg] = creg;
            } else {
                unsigned int wv = (((nonce6 << 10) | ((unsigned)(t + 1) & 1023u)) << 16)
                                  | (unsigned int)hb;
                unsigned int* hp = hx + ((size_t)(((t + 1) & 1) * 8 + G)) * 8192
                                      + nloc * 1024 + jg;
                asm volatile("global_store_dword %0, %1, off sc0 sc1"
                             :: "v"(hp), "v"(wv) : "memory");
            }
            y[((size_t)ng << 19) + ((size_t)t << 10) + jg] = hh;
        }
    }
}

extern "C" void kernel_launch(void* const* d_in, const int* in_sizes, int n_in,
                              void* d_out, int out_size, void* d_ws, size_t ws_size,
                              hipStream_t stream) {
    const float* x   = (const float*)d_in[0];
    const float* wih = (const float*)d_in[1];
    const float* whh = (const float*)d_in[2];
    const float* bih = (const float*)d_in[3];
    const float* bhh = (const float*)d_in[4];
    float* y = (float*)d_out;

    char* ws = (char*)d_ws;
    unsigned short* Whh_bf = (unsigned short*)ws;                           // 8 MiB
    unsigned short* Wih_bf = (unsigned short*)(ws + ((size_t)8 << 20));     // 8 MiB
    unsigned short* xgc    = (unsigned short*)(ws + ((size_t)16 << 20));    // 64 MiB (f16)
    char* SB               = ws + ((size_t)80 << 20);
    float* biasc           = (float*)SB;                                    // 16 KiB
    char* zb               = SB + (16u << 10);
    unsigned short* hcan   = (unsigned short*)zb;                           // 128 KiB
    float* cws             = (float*)(zb + (128u << 10));                   // 256 KiB
    unsigned int* hx       = (unsigned int*)(zb + (384u << 10));            // 512 KiB
    unsigned int* nonce    = (unsigned int*)(zb + (896u << 10));            // 4 B (NOT zeroed)
    unsigned short* xbc    = (unsigned short*)(ws + ((size_t)81 << 20));    // 16 MiB (fast path)
    const int nz = (896 << 10) / 4;
    if (ws_size < ((size_t)81 << 20)) return;
    const bool fast = ws_size >= ((size_t)98 << 20);

    hipLaunchKernelGGL(cvt_w2, dim3(4096), dim3(256), 0, stream, whh, wih, Whh_bf, Wih_bf);
    hipLaunchKernelGGL(init_kernel, dim3(896), dim3(256), 0, stream,
                       bih, bhh, biasc, (unsigned int*)zb, nz, nonce);

    for (int chk = 0; chk < NCH; ++chk) {
        int t0 = chk * TCH;
        if (fast) {
            hipLaunchKernelGGL(cvt_xb, dim3(4096), dim3(256), 0, stream, x, xbc, t0);
            hipLaunchKernelGGL(xg_gemm_bf, dim3(2048), dim3(256), 0, stream, xbc, Wih_bf, xgc);
        } else {
            hipLaunchKernelGGL(xg_gemm, dim3(2048), dim3(256), 0, stream, x, Wih_bf, xgc, t0);
        }
        void* args[] = {(void*)&Whh_bf, (void*)&xgc, (void*)&biasc, (void*)&hcan,
                        (void*)&hx, (void*)&cws, (void*)&nonce, (void*)&y, (void*)&t0};
        hipLaunchCooperativeKernel((const void*)lstm_persist, dim3(NWG), dim3(512),
                                   args, 0, stream);
    }
}

// Round 16
// 2078.196 us; speedup vs baseline: 1.2896x; 1.0502x over previous
//
#include <hip/hip_runtime.h>

#define HID 1024
#define G4 4096
#define TCH 128
#define NCH 4
#define NWG 256

typedef short short8 __attribute__((ext_vector_type(8)));
typedef float f32x4 __attribute__((ext_vector_type(4)));
typedef unsigned int u32x4 __attribute__((ext_vector_type(4)));

static __device__ __forceinline__ unsigned short f2bf(float f) {
    unsigned int u = __builtin_bit_cast(unsigned int, f);
    u += 0x7fffu + ((u >> 16) & 1u);
    return (unsigned short)(u >> 16);
}
static __device__ __forceinline__ unsigned short f2h(float v) {
    _Float16 h = (_Float16)v;
    return __builtin_bit_cast(unsigned short, h);
}
static __device__ __forceinline__ float h2f(unsigned short u) {
    return (float)__builtin_bit_cast(_Float16, u);
}

// fused fp32 -> bf16 convert for BOTH weight matrices (one launch)
__global__ void cvt_w2(const float* __restrict__ whh, const float* __restrict__ wih,
                       unsigned short* __restrict__ whh_bf, unsigned short* __restrict__ wih_bf) {
    int idx = blockIdx.x * blockDim.x + threadIdx.x;   // 1M threads, 512K groups each
    const float* src;
    unsigned short* dst;
    if (idx < 524288) { src = whh + (size_t)idx * 8; dst = whh_bf + (size_t)idx * 8; }
    else { int k = idx - 524288; src = wih + (size_t)k * 8; dst = wih_bf + (size_t)k * 8; }
    float4 a = *(const float4*)src;
    float4 b = *(const float4*)(src + 4);
    short8 v;
    v[0]=(short)f2bf(a.x); v[1]=(short)f2bf(a.y); v[2]=(short)f2bf(a.z); v[3]=(short)f2bf(a.w);
    v[4]=(short)f2bf(b.x); v[5]=(short)f2bf(b.y); v[6]=(short)f2bf(b.z); v[7]=(short)f2bf(b.w);
    *(short8*)dst = v;
}

// x chunk (N,T,D slice) f32 -> xbc [tl*64+n][d] bf16 (fast path only)
__global__ void cvt_xb(const float* __restrict__ x, unsigned short* __restrict__ xbc, int t0) {
    int idx = blockIdx.x * blockDim.x + threadIdx.x;   // 1M threads
    int d = (idx & 127) * 8;
    int m = idx >> 7;                // 0..8191
    int tl = m >> 6, n = m & 63;
    const float* sp = x + ((size_t)n * 512 + (size_t)(t0 + tl)) * 1024 + d;
    float4 a = *(const float4*)sp;
    float4 b = *(const float4*)(sp + 4);
    short8 v;
    v[0]=(short)f2bf(a.x); v[1]=(short)f2bf(a.y); v[2]=(short)f2bf(a.z); v[3]=(short)f2bf(a.w);
    v[4]=(short)f2bf(b.x); v[5]=(short)f2bf(b.y); v[6]=(short)f2bf(b.z); v[7]=(short)f2bf(b.w);
    *(short8*)(xbc + (size_t)m * 1024 + d) = v;
}

// zero state region (hcan, cws, hx), combine biases, bump per-replay nonce
__global__ void init_kernel(const float* __restrict__ bih, const float* __restrict__ bhh,
                            float* __restrict__ biasc, unsigned int* __restrict__ zbase,
                            int nz, unsigned int* __restrict__ nonce) {
    int i = blockIdx.x * blockDim.x + threadIdx.x;
    if (i < nz) zbase[i] = 0u;
    if (i < G4) biasc[i] = bih[i] + bhh[i];
    if (i == 0) nonce[0] = nonce[0] + 1u;
}

// xg[m][g] = sum_k A[m][k]*Wih[g][k]; output f16 bits. SLOW path: A from f32 x.
__global__ __launch_bounds__(256) void xg_gemm(
    const float* __restrict__ x,            // [64][512][1024] fp32
    const unsigned short* __restrict__ wb,  // Wih_bf [4096][1024]
    unsigned short* __restrict__ xg,        // [TCH*64][4096] f16 chunk
    int t0) {
    __shared__ unsigned short Al[128][72];
    __shared__ unsigned short Bl[128][72];
    const int tid = threadIdx.x, w = tid >> 6, lane = tid & 63;
    const int bm = blockIdx.x >> 5, bn = blockIdx.x & 31;
    const int wr = w >> 1, wc = w & 1;
    const int fr = lane & 15, kg = lane >> 4;
    f32x4 acc[4][4];
    #pragma unroll
    for (int i = 0; i < 4; ++i)
        #pragma unroll
        for (int j = 0; j < 4; ++j) acc[i][j] = (f32x4){0.f,0.f,0.f,0.f};

    for (int kt = 0; kt < 16; ++kt) {
        __syncthreads();
        #pragma unroll
        for (int c = 0; c < 4; ++c) {
            int idx = c * 256 + tid;
            int row = idx >> 3, co = (idx & 7) * 8;
            int m = bm * 128 + row;
            const float* sp = x + ((size_t)(m & 63) * 512 + (size_t)(t0 + (m >> 6))) * 1024
                                + kt * 64 + co;
            float4 a = *(const float4*)sp;
            float4 b = *(const float4*)(sp + 4);
            short8 v;
            v[0]=(short)f2bf(a.x); v[1]=(short)f2bf(a.y); v[2]=(short)f2bf(a.z); v[3]=(short)f2bf(a.w);
            v[4]=(short)f2bf(b.x); v[5]=(short)f2bf(b.y); v[6]=(short)f2bf(b.z); v[7]=(short)f2bf(b.w);
            *(short8*)&Al[row][co] = v;
            *(short8*)&Bl[row][co] = *(const short8*)(wb + (size_t)(bn * 128 + row) * 1024 + kt * 64 + co);
        }
        __syncthreads();
        #pragma unroll
        for (int kb = 0; kb < 2; ++kb) {
            short8 af[4], bf_[4];
            #pragma unroll
            for (int mi = 0; mi < 4; ++mi)
                af[mi] = *(const short8*)&Al[wr*64 + mi*16 + fr][kb*32 + kg*8];
            #pragma unroll
            for (int ni = 0; ni < 4; ++ni)
                bf_[ni] = *(const short8*)&Bl[wc*64 + ni*16 + fr][kb*32 + kg*8];
            #pragma unroll
            for (int mi = 0; mi < 4; ++mi)
                #pragma unroll
                for (int ni = 0; ni < 4; ++ni)
                    acc[mi][ni] = __builtin_amdgcn_mfma_f32_16x16x32_bf16(af[mi], bf_[ni], acc[mi][ni], 0, 0, 0);
        }
    }
    #pragma unroll
    for (int mi = 0; mi < 4; ++mi)
        #pragma unroll
        for (int ni = 0; ni < 4; ++ni)
            #pragma unroll
            for (int r = 0; r < 4; ++r) {
                int row = bm*128 + wr*64 + mi*16 + kg*4 + r;
                int col = bn*128 + wc*64 + ni*16 + fr;
                xg[(size_t)row * 4096 + col] = f2h(acc[mi][ni][r]);
            }
}

// FAST path: identical math, A staged as bf16 short8 from pre-converted xbc.
__global__ __launch_bounds__(256) void xg_gemm_bf(
    const unsigned short* __restrict__ xbc, // [8192][1024] bf16 chunk A
    const unsigned short* __restrict__ wb,  // Wih_bf [4096][1024]
    unsigned short* __restrict__ xg) {      // [TCH*64][4096] f16 chunk
    __shared__ unsigned short Al[128][72];
    __shared__ unsigned short Bl[128][72];
    const int tid = threadIdx.x, w = tid >> 6, lane = tid & 63;
    const int bm = blockIdx.x >> 5, bn = blockIdx.x & 31;
    const int wr = w >> 1, wc = w & 1;
    const int fr = lane & 15, kg = lane >> 4;
    f32x4 acc[4][4];
    #pragma unroll
    for (int i = 0; i < 4; ++i)
        #pragma unroll
        for (int j = 0; j < 4; ++j) acc[i][j] = (f32x4){0.f,0.f,0.f,0.f};

    for (int kt = 0; kt < 16; ++kt) {
        __syncthreads();
        #pragma unroll
        for (int c = 0; c < 4; ++c) {
            int idx = c * 256 + tid;
            int row = idx >> 3, co = (idx & 7) * 8;
            *(short8*)&Al[row][co] = *(const short8*)(xbc + (size_t)(bm * 128 + row) * 1024 + kt * 64 + co);
            *(short8*)&Bl[row][co] = *(const short8*)(wb  + (size_t)(bn * 128 + row) * 1024 + kt * 64 + co);
        }
        __syncthreads();
        #pragma unroll
        for (int kb = 0; kb < 2; ++kb) {
            short8 af[4], bf_[4];
            #pragma unroll
            for (int mi = 0; mi < 4; ++mi)
                af[mi] = *(const short8*)&Al[wr*64 + mi*16 + fr][kb*32 + kg*8];
            #pragma unroll
            for (int ni = 0; ni < 4; ++ni)
                bf_[ni] = *(const short8*)&Bl[wc*64 + ni*16 + fr][kb*32 + kg*8];
            #pragma unroll
            for (int mi = 0; mi < 4; ++mi)
                #pragma unroll
                for (int ni = 0; ni < 4; ++ni)
                    acc[mi][ni] = __builtin_amdgcn_mfma_f32_16x16x32_bf16(af[mi], bf_[ni], acc[mi][ni], 0, 0, 0);
        }
    }
    #pragma unroll
    for (int mi = 0; mi < 4; ++mi)
        #pragma unroll
        for (int ni = 0; ni < 4; ++ni)
            #pragma unroll
            for (int r = 0; r < 4; ++r) {
                int row = bm*128 + wr*64 + mi*16 + kg*4 + r;
                int col = bn*128 + wc*64 + ni*16 + fr;
                xg[(size_t)row * 4096 + col] = f2h(acc[mi][ni][r]);
            }
}

// Persistent LSTM chunk (128 steps). R15 structure; ONE theme: decontaminate the
// poll's vmcnt(0) FIFO (vmcnt waits for ALL older VMEM ops, in issue order):
//  - y values buffered in 4 NAMED registers (static indexing, rule #20) and
//    flushed as a batch every 4 steps -> the per-step HBM y-store ack leaves the
//    poll's wait window on 3 of 4 steps.
//  - xg prefetch shifted one step ahead (issued under MFMA/pointwise cover) so
//    its HBM fetch retires before the next poll's vmcnt(0).
// Math bit-identical to R15.
__global__ __launch_bounds__(512, 2) void lstm_persist(
    const unsigned short* __restrict__ whh,   // Whh_bf [4096][1024]
    const unsigned short* __restrict__ xg,    // [TCH*64][4096] f16 bits
    const float* __restrict__ biasc,          // [4096]
    unsigned short* __restrict__ hcan,        // [64][1024] bf16 chunk-boundary h
    unsigned int* __restrict__ hx,            // [2 par][8 G][8][1024] u32 tagged h
    float* __restrict__ cws,                  // [64][1024] chunk-boundary c
    const unsigned int* __restrict__ nonce,   // [1]
    float* __restrict__ y, int t0) {
    __shared__ unsigned short hA[2][8192];    // [par][8][1024] bf16, XOR-swizzled

    const int tid = threadIdx.x, w = tid >> 6, lane = tid & 63;
    const int G = (int)(blockIdx.x >> 5);
    const int l = (int)(blockIdx.x & 31);

    const int c  = lane & 15, kg = lane >> 4;
    const int q  = c & 3;                  // gate type of this lane's B column
    const int e  = c >> 2;                 // unit-within-4 of this lane's B column
    const int jg = l * 32 + w * 4 + e;     // global hidden unit (output lanes <32)
    const int nloc = kg * 4 + q;           // group-local batch row (output lanes <32)
    const unsigned int nonce6 = nonce[0] & 63u;

    short8 bfr[32];   // Whh row (q*1024 + jg), K=1024
    {
        const unsigned short* wp = whh + ((size_t)(q * 1024 + jg) << 10) + kg * 8;
        #pragma unroll
        for (int kb = 0; kb < 32; ++kb) bfr[kb] = *(const short8*)(wp + kb * 32);
    }
    const float bi = biasc[jg],        bfv = biasc[1024 + jg];
    const float bg = biasc[2048 + jg], bov = biasc[3072 + jg];

    float creg = 0.f;
    if (lane < 32) creg = cws[((size_t)(G * 8 + nloc) << 10) + jg];
    __syncthreads();

    const int sn = w;   // staging batch row 0..7 (one per wave)
    const int row = lane & 15;
    const unsigned rsw = (unsigned)(row & 7);
    const unsigned b0off = ((unsigned)(kg) ^ rsw) << 4;

    // y register buffer (static names) + one-step-ahead xg prefetch registers
    float y0 = 0.f, y1 = 0.f, y2 = 0.f, y3 = 0.f;
    unsigned short xn_i = 0, xn_f = 0, xn_g = 0, xn_o = 0;
    const unsigned short* xbase = xg + ((size_t)(G * 8 + nloc) << 12) + jg;
    if (lane < 32) {   // prefetch xg for s = 0
        xn_i = xbase[0]; xn_f = xbase[1024]; xn_g = xbase[2048]; xn_o = xbase[3072];
    }
    float* ybase = y + ((size_t)(G * 8 + nloc) << 19) + ((size_t)t0 << 10) + jg;

    for (int s = 0; s < TCH; ++s) {
        const int t = t0 + s;
        // rotate prefetched xg into current
        const unsigned short xi = xn_i, xf = xn_f, xgv = xn_g, xo = xn_o;

        // ---- acquire h(t) row sn: selective-retry poll (re-read only stale quads) ----
        short8 v0, v1;
        if (s == 0) {
            const unsigned short* hp = hcan + ((size_t)(G * 8 + sn) << 10);
            v0 = *(const short8*)(hp + lane * 8);
            v1 = *(const short8*)(hp + 512 + lane * 8);
        } else {
            const unsigned int* pp = hx + ((size_t)((t & 1) * 8 + G)) * 8192 + sn * 1024 + lane * 8;
            const unsigned int xm = ((nonce6 << 10) | ((unsigned)t & 1023u)) << 16;
            u32x4 w0, w1, w2, w3;
            unsigned int okm = 0;   // bit k = quad k latched
            int guard = 0;
            while (true) {
                if (!(okm & 1u))
                    asm volatile("global_load_dwordx4 %0, %1, off sc0 sc1" : "=v"(w0) : "v"(pp)       : "memory");
                if (!(okm & 2u))
                    asm volatile("global_load_dwordx4 %0, %1, off sc0 sc1" : "=v"(w1) : "v"(pp + 4)   : "memory");
                if (!(okm & 4u))
                    asm volatile("global_load_dwordx4 %0, %1, off sc0 sc1" : "=v"(w2) : "v"(pp + 512) : "memory");
                if (!(okm & 8u))
                    asm volatile("global_load_dwordx4 %0, %1, off sc0 sc1" : "=v"(w3) : "v"(pp + 516) : "memory");
                asm volatile("s_waitcnt vmcnt(0)"
                             : "+v"(w0), "+v"(w1), "+v"(w2), "+v"(w3) :: "memory");
                unsigned int a0 = (w0[0]^xm)|(w0[1]^xm)|(w0[2]^xm)|(w0[3]^xm);
                unsigned int a1 = (w1[0]^xm)|(w1[1]^xm)|(w1[2]^xm)|(w1[3]^xm);
                unsigned int a2 = (w2[0]^xm)|(w2[1]^xm)|(w2[2]^xm)|(w2[3]^xm);
                unsigned int a3 = (w3[0]^xm)|(w3[1]^xm)|(w3[2]^xm)|(w3[3]^xm);
                okm |= ((a0 >> 16) == 0u) ? 1u : 0u;
                okm |= ((a1 >> 16) == 0u) ? 2u : 0u;
                okm |= ((a2 >> 16) == 0u) ? 4u : 0u;
                okm |= ((a3 >> 16) == 0u) ? 8u : 0u;
                if (__all((int)(okm == 15u)) || ++guard > 100000) break;
            }
            #pragma unroll
            for (int ee = 0; ee < 4; ++ee) {
                v0[ee]     = (short)(w0[ee] & 0xffffu);
                v0[4 + ee] = (short)(w1[ee] & 0xffffu);
                v1[ee]     = (short)(w2[ee] & 0xffffu);
                v1[4 + ee] = (short)(w3[ee] & 0xffffu);
            }
        }
        {   // stage: slots lane^sn (elems 8L..) and 64+(lane^sn) (elems 512+8L..)
            char* base = (char*)&hA[s & 1][0] + sn * 2048 + (((unsigned)(lane ^ sn)) << 4);
            *(short8*)(base)        = v0;
            *(short8*)(base + 1024) = v1;
        }
        __syncthreads();   // the ONLY barrier per step

        // ---- xg prefetch for step s+1 (retires under MFMA+pointwise cover) ----
        if (lane < 32) {
            int s2 = (s + 1 < TCH) ? s + 1 : s;   // clamp: harmless dup load on last step
            const unsigned short* xp = xbase + ((size_t)(s2 * 64) << 12);
            xn_i = xp[0]; xn_f = xp[1024]; xn_g = xp[2048]; xn_o = xp[3072];
        }

        // ---- recurrent MFMA: hoisted base addressing, immediate offsets ----
        f32x4 acc0 = {0.f,0.f,0.f,0.f}, acc1 = {0.f,0.f,0.f,0.f};
        {
            const char* bas = (const char*)&hA[s & 1][0] + (row & 7) * 2048;
            const char* p0 = bas + b0off;
            const char* p1 = bas + (b0off ^ 64u);
            #pragma unroll
            for (int kb = 0; kb < 32; kb += 2) {
                short8 a0 = *(const short8*)(p0 + kb * 64);
                short8 a1 = *(const short8*)(p1 + kb * 64);
                acc0 = __builtin_amdgcn_mfma_f32_16x16x32_bf16(a0, bfr[kb],     acc0, 0, 0, 0);
                acc1 = __builtin_amdgcn_mfma_f32_16x16x32_bf16(a1, bfr[kb + 1], acc1, 0, 0, 0);
            }
            #pragma unroll
            for (int r = 0; r < 4; ++r) acc0[r] += acc1[r];
        }
        // ---- wave-local gate gather: 4 shuffle rounds (no LDS, no barrier) ----
        float iv = 0.f, fv = 0.f, gv = 0.f, ov = 0.f;
        #pragma unroll
        for (int j = 0; j < 4; ++j) {
            int sel = (q + j) & 3;
            float sv = (sel == 0) ? acc0[0] : (sel == 1) ? acc0[1]
                     : (sel == 2) ? acc0[2] : acc0[3];
            int src = (lane & ~3) | ((q - j) & 3);
            float rv = __shfl(sv, src, 64);
            int g = (q - j) & 3;
            iv = (g == 0) ? rv : iv;
            fv = (g == 1) ? rv : fv;
            gv = (g == 2) ? rv : gv;
            ov = (g == 3) ? rv : ov;
        }
        // ---- pointwise (lanes < 32 hold the 8 real rows x this wave's 4 units) ----
        if (lane < 32) {
            float ivv = iv + h2f(xi)  + bi;
            float fvv = fv + h2f(xf)  + bfv;
            float gvv = gv + h2f(xgv) + bg;
            float ovv = ov + h2f(xo)  + bov;
            ivv = 1.f / (1.f + __expf(-ivv));
            fvv = 1.f / (1.f + __expf(-fvv));
            ovv = 1.f / (1.f + __expf(-ovv));
            float eg = __expf(2.f * gvv);
            gvv = 1.f - 2.f / (eg + 1.f);
            creg = fvv * creg + ivv * gvv;
            float ec = __expf(2.f * creg);
            float hh = ovv * (1.f - 2.f / (ec + 1.f));
            unsigned short hb = f2bf(hh);
            int ng = G * 8 + nloc;
            if (s == TCH - 1) {
                hcan[((size_t)ng << 10) + jg] = hb;    // plain: next launch reads it
                cws[((size_t)ng << 10) + jg] = creg;
            } else {
                unsigned int wv = (((nonce6 << 10) | ((unsigned)(t + 1) & 1023u)) << 16)
                                  | (unsigned int)hb;
                unsigned int* hp = hx + ((size_t)(((t + 1) & 1) * 8 + G)) * 8192
                                      + nloc * 1024 + jg;
                asm volatile("global_store_dword %0, %1, off sc0 sc1"
                             :: "v"(hp), "v"(wv) : "memory");
            }
            // ---- y register buffer: static names; batch-flush every 4 steps ----
            int ph = s & 3;
            y0 = (ph == 0) ? hh : y0;
            y1 = (ph == 1) ? hh : y1;
            y2 = (ph == 2) ? hh : y2;
            y3 = (ph == 3) ? hh : y3;
            if (ph == 3) {
                float* yp = ybase + ((size_t)(s - 3) << 10);
                yp[0]    = y0;
                yp[1024] = y1;
                yp[2048] = y2;
                yp[3072] = y3;
            }
        }
    }
}

extern "C" void kernel_launch(void* const* d_in, const int* in_sizes, int n_in,
                              void* d_out, int out_size, void* d_ws, size_t ws_size,
                              hipStream_t stream) {
    const float* x   = (const float*)d_in[0];
    const float* wih = (const float*)d_in[1];
    const float* whh = (const float*)d_in[2];
    const float* bih = (const float*)d_in[3];
    const float* bhh = (const float*)d_in[4];
    float* y = (float*)d_out;

    char* ws = (char*)d_ws;
    unsigned short* Whh_bf = (unsigned short*)ws;                           // 8 MiB
    unsigned short* Wih_bf = (unsigned short*)(ws + ((size_t)8 << 20));     // 8 MiB
    unsigned short* xgc    = (unsigned short*)(ws + ((size_t)16 << 20));    // 64 MiB (f16)
    char* SB               = ws + ((size_t)80 << 20);
    float* biasc           = (float*)SB;                                    // 16 KiB
    char* zb               = SB + (16u << 10);
    unsigned short* hcan   = (unsigned short*)zb;                           // 128 KiB
    float* cws             = (float*)(zb + (128u << 10));                   // 256 KiB
    unsigned int* hx       = (unsigned int*)(zb + (384u << 10));            // 512 KiB
    unsigned int* nonce    = (unsigned int*)(zb + (896u << 10));            // 4 B (NOT zeroed)
    unsigned short* xbc    = (unsigned short*)(ws + ((size_t)81 << 20));    // 16 MiB (fast path)
    const int nz = (896 << 10) / 4;
    if (ws_size < ((size_t)81 << 20)) return;
    const bool fast = ws_size >= ((size_t)98 << 20);

    hipLaunchKernelGGL(cvt_w2, dim3(4096), dim3(256), 0, stream, whh, wih, Whh_bf, Wih_bf);
    hipLaunchKernelGGL(init_kernel, dim3(896), dim3(256), 0, stream,
                       bih, bhh, biasc, (unsigned int*)zb, nz, nonce);

    for (int chk = 0; chk < NCH; ++chk) {
        int t0 = chk * TCH;
        if (fast) {
            hipLaunchKernelGGL(cvt_xb, dim3(4096), dim3(256), 0, stream, x, xbc, t0);
            hipLaunchKernelGGL(xg_gemm_bf, dim3(2048), dim3(256), 0, stream, xbc, Wih_bf, xgc);
        } else {
            hipLaunchKernelGGL(xg_gemm, dim3(2048), dim3(256), 0, stream, x, Wih_bf, xgc, t0);
        }
        void* args[] = {(void*)&Whh_bf, (void*)&xgc, (void*)&biasc, (void*)&hcan,
                        (void*)&hx, (void*)&cws, (void*)&nonce, (void*)&y, (void*)&t0};
        hipLaunchCooperativeKernel((const void*)lstm_persist, dim3(NWG), dim3(512),
                                   args, 0, stream);
    }
}